// Round 2
// baseline (2901.933 us; speedup 1.0000x reference)
//
#include <hip/hip_runtime.h>
#include <math.h>

// MaxMarginLoss: B=4,S=512,D=512,V=32000, gamma=0.5, eps=1e-12
// score[r,v] = (out_norm[r] - tgt_emb[r]) . voc_norm[v]   (argmax over v, first-idx ties)
// loss = mean over non-pad rows of max(gamma + cos(out,voc[jmax]) - cos(out,voc[tgt]), 0)

#define Bb 4
#define Ss 512
#define Dd 512
#define Vv 32000
#define ROWS (Bb * Ss)          // 2048
#define NSTRIP 8
#define STRIPV (Vv / NSTRIP)    // 4000
#define RT 32                   // rows per block in score kernel

__device__ __forceinline__ float waveReduceSum(float x) {
#pragma unroll
  for (int m = 32; m >= 1; m >>= 1) x += __shfl_xor(x, m, 64);
  return x;
}

// A: per-row prep. out_norm row, u = out_norm - emb[target], cos_target (all fp32 exact).
__global__ __launch_bounds__(256) void prep_rows(
    const float* __restrict__ preds, const float* __restrict__ emb,
    const int* __restrict__ target,
    float* __restrict__ o_rows, float* __restrict__ u_rows,
    float* __restrict__ cos_tgt) {
  int row = blockIdx.x;
  int b = row >> 9, s = row & (Ss - 1);
  int tid = threadIdx.x;
  int wave = tid >> 6, lane = tid & 63;
  const float* p = preds + (size_t)b * Dd * Ss + s;
  float x0 = p[(size_t)tid * Ss];
  float x1 = p[(size_t)(tid + 256) * Ss];
  __shared__ float red[12];
  float ss = waveReduceSum(x0 * x0 + x1 * x1);
  if (lane == 0) red[wave] = ss;
  __syncthreads();
  float inv = 1.0f / fmaxf(sqrtf(red[0] + red[1] + red[2] + red[3]), 1e-12f);
  float o0 = x0 * inv, o1 = x1 * inv;
  o_rows[(size_t)row * Dd + tid] = o0;
  o_rows[(size_t)row * Dd + tid + 256] = o1;
  int t = target[row];
  const float* et = emb + (size_t)t * Dd;
  float e0 = et[tid], e1 = et[tid + 256];
  u_rows[(size_t)row * Dd + tid] = o0 - e0;
  u_rows[(size_t)row * Dd + tid + 256] = o1 - e1;
  float ss2 = waveReduceSum(e0 * e0 + e1 * e1);
  float dt = waveReduceSum(o0 * e0 + o1 * e1);
  if (lane == 0) { red[4 + wave] = ss2; red[8 + wave] = dt; }
  __syncthreads();
  if (tid == 0) {
    float n2 = red[4] + red[5] + red[6] + red[7];
    float dd = red[8] + red[9] + red[10] + red[11];
    cos_tgt[row] = dd * (1.0f / fmaxf(sqrtf(n2), 1e-12f));
  }
}

// B: inv_norm[v] = 1/max(||emb[v]||, eps). One wave per v.
__global__ __launch_bounds__(256) void voc_inv(const float* __restrict__ emb,
                                               float* __restrict__ inv_norm) {
  int v = blockIdx.x * 4 + (threadIdx.x >> 6);
  int lane = threadIdx.x & 63;
  const float* e = emb + (size_t)v * Dd;
  float ss = 0.f;
#pragma unroll
  for (int i = 0; i < Dd / 64; ++i) {
    float x = e[lane + 64 * i];
    ss += x * x;
  }
  ss = waveReduceSum(ss);
  if (lane == 0) inv_norm[v] = 1.0f / fmaxf(sqrtf(ss), 1e-12f);
}

// C: fused score + argmax. Block: 32 rows (LDS), strip of 4000 v.
// Thread: 8 rows x 4 vocab register tile; 128 FMA per k-step.
__global__ __launch_bounds__(256) void score_argmax(
    const float* __restrict__ u_rows, const float* __restrict__ emb,
    const float* __restrict__ inv_norm,
    float* __restrict__ part_s, int* __restrict__ part_i) {
  __shared__ float4 sU[RT * (Dd / 4)];  // 32 rows x 512 f32 = 64 KB
  int tid = threadIdx.x;
  int rowtile = blockIdx.x;  // 0..63
  int strip = blockIdx.y;    // 0..7
  int row0 = rowtile * RT;
  const float4* ug = (const float4*)(u_rows + (size_t)row0 * Dd);
  for (int f = tid; f < RT * (Dd / 4); f += 256) sU[f] = ug[f];
  __syncthreads();
  int rg = tid >> 6, vlane = tid & 63;  // wave rg owns rows rg*8..rg*8+7
  const float4* uB = sU + rg * 8 * (Dd / 4);
  float best_s[8];
  int best_i[8];
#pragma unroll
  for (int r = 0; r < 8; ++r) { best_s[r] = -INFINITY; best_i[r] = 0; }
  int vbase = strip * STRIPV;
  for (int it = 0; it < (STRIPV + 255) / 256; ++it) {
    int v0 = vbase + it * 256 + vlane;
    // clamp load addresses; merges are guarded by vj < Vv (duplicate v across
    // strips is harmless for argmax).
    const float4* e0p = (const float4*)(emb + (size_t)min(v0, Vv - 1) * Dd);
    const float4* e1p = (const float4*)(emb + (size_t)min(v0 + 64, Vv - 1) * Dd);
    const float4* e2p = (const float4*)(emb + (size_t)min(v0 + 128, Vv - 1) * Dd);
    const float4* e3p = (const float4*)(emb + (size_t)min(v0 + 192, Vv - 1) * Dd);
    float acc[8][4] = {};
#pragma unroll 2
    for (int k = 0; k < Dd / 4; ++k) {
      float4 e0 = e0p[k], e1 = e1p[k], e2 = e2p[k], e3 = e3p[k];
#pragma unroll
      for (int r = 0; r < 8; ++r) {
        float4 u = uB[r * (Dd / 4) + k];
        acc[r][0] += u.x * e0.x + u.y * e0.y + u.z * e0.z + u.w * e0.w;
        acc[r][1] += u.x * e1.x + u.y * e1.y + u.z * e1.z + u.w * e1.w;
        acc[r][2] += u.x * e2.x + u.y * e2.y + u.z * e2.z + u.w * e2.w;
        acc[r][3] += u.x * e3.x + u.y * e3.y + u.z * e3.z + u.w * e3.w;
      }
    }
#pragma unroll
    for (int j = 0; j < 4; ++j) {
      int vj = v0 + 64 * j;
      if (vj < Vv) {
        float inv = inv_norm[vj];
#pragma unroll
        for (int r = 0; r < 8; ++r) {
          float sc = acc[r][j] * inv;
          if (sc > best_s[r] || (sc == best_s[r] && vj < best_i[r])) {
            best_s[r] = sc;
            best_i[r] = vj;
          }
        }
      }
    }
  }
  // wave butterfly argmax merge (first-index tie-break)
#pragma unroll
  for (int m = 1; m < 64; m <<= 1) {
#pragma unroll
    for (int r = 0; r < 8; ++r) {
      float os = __shfl_xor(best_s[r], m, 64);
      int oi = __shfl_xor(best_i[r], m, 64);
      if (os > best_s[r] || (os == best_s[r] && oi < best_i[r])) {
        best_s[r] = os;
        best_i[r] = oi;
      }
    }
  }
  if (vlane == 0) {
#pragma unroll
    for (int r = 0; r < 8; ++r) {
      int row = row0 + rg * 8 + r;
      part_s[strip * ROWS + row] = best_s[r];
      part_i[strip * ROWS + row] = best_i[r];
    }
  }
}

// D: per row — merge strip partials, recompute cos at jmax in fp32, hinge.
__global__ __launch_bounds__(256) void row_final(
    const float* __restrict__ o_rows, const float* __restrict__ emb,
    const float* __restrict__ inv_norm, const float* __restrict__ cos_tgt,
    const int* __restrict__ target, const int* __restrict__ pad_id,
    const float* __restrict__ part_s, const int* __restrict__ part_i,
    float* __restrict__ diffs) {
  int wave = threadIdx.x >> 6, lane = threadIdx.x & 63;
  int row = blockIdx.x * 4 + wave;
  float bs = -INFINITY;
  int bi = 0;
  if (lane < NSTRIP) {
    bs = part_s[lane * ROWS + row];
    bi = part_i[lane * ROWS + row];
  }
#pragma unroll
  for (int m = 1; m < 64; m <<= 1) {
    float os = __shfl_xor(bs, m, 64);
    int oi = __shfl_xor(bi, m, 64);
    if (os > bs || (os == bs && oi < bi)) { bs = os; bi = oi; }
  }
  const float* o = o_rows + (size_t)row * Dd;
  const float* e = emb + (size_t)bi * Dd;
  float d = 0.f;
#pragma unroll
  for (int i = 0; i < Dd / 64; ++i) d += o[lane + 64 * i] * e[lane + 64 * i];
  d = waveReduceSum(d);
  if (lane == 0) {
    float cmax = d * inv_norm[bi];
    int t = target[row];
    float df = fmaxf(0.5f + cmax - cos_tgt[row], 0.0f);
    diffs[row] = (t != pad_id[0]) ? df : 0.0f;
  }
}

// F: masked mean.
__global__ __launch_bounds__(256) void reduce_final(
    const float* __restrict__ diffs, const int* __restrict__ target,
    const int* __restrict__ pad_id, float* __restrict__ out) {
  int tid = threadIdx.x;
  int pid = pad_id[0];
  float s = 0.f, c = 0.f;
  for (int i = tid; i < ROWS; i += 256) {
    s += diffs[i];
    c += (target[i] != pid) ? 1.0f : 0.0f;
  }
  s = waveReduceSum(s);
  c = waveReduceSum(c);
  __shared__ float rs[4], rc[4];
  int wave = tid >> 6, lane = tid & 63;
  if (lane == 0) { rs[wave] = s; rc[wave] = c; }
  __syncthreads();
  if (tid == 0) out[0] = (rs[0] + rs[1] + rs[2] + rs[3]) / (rc[0] + rc[1] + rc[2] + rc[3]);
}

extern "C" void kernel_launch(void* const* d_in, const int* in_sizes, int n_in,
                              void* d_out, int out_size, void* d_ws, size_t ws_size,
                              hipStream_t stream) {
  const float* preds = (const float*)d_in[0];
  const float* emb = (const float*)d_in[1];
  const int* target = (const int*)d_in[2];
  const int* pad_id = (const int*)d_in[3];
  float* ws = (float*)d_ws;
  // ws layout (floats): total ~8.7 MB
  float* o_rows = ws;                   // 2048*512
  float* u_rows = ws + 1048576;         // 2048*512
  float* cos_tgt = ws + 2097152;        // 2048
  float* inv_norm = ws + 2099200;       // 32000
  float* part_s = ws + 2131200;         // 8*2048
  int* part_i = (int*)(ws + 2147584);   // 8*2048
  float* diffs = ws + 2163968;          // 2048

  prep_rows<<<ROWS, 256, 0, stream>>>(preds, emb, target, o_rows, u_rows, cos_tgt);
  voc_inv<<<Vv / 4, 256, 0, stream>>>(emb, inv_norm);
  dim3 g(ROWS / RT, NSTRIP);
  score_argmax<<<g, 256, 0, stream>>>(u_rows, emb, inv_norm, part_s, part_i);
  row_final<<<ROWS / 4, 256, 0, stream>>>(o_rows, emb, inv_norm, cos_tgt, target,
                                          pad_id, part_s, part_i, diffs);
  reduce_final<<<1, 256, 0, stream>>>(diffs, target, pad_id, (float*)d_out);
}

// Round 3
// 230.183 us; speedup vs baseline: 12.6071x; 12.6071x over previous
//
#include <hip/hip_runtime.h>
#include <math.h>

// MaxMarginLoss: B=4,S=512,D=512,V=32000, gamma=0.5, eps=1e-12
// score[r,v] = (out_norm[r] - tgt_emb[r]) . voc_norm[v]  -> argmax_v (first-idx ties)
// loss = mean over non-pad rows of max(gamma + cos(out,voc[jmax]) - cos(out,voc[tgt]), 0)
//
// R3: score pass = bf16 MFMA gemm_bt (m97 structure) + fused argmax epilogue.
// jmax decided on bf16 scores (error ~3e-3, flips only near-ties; loss impact
// ~1e-4 << 1e-2 threshold); cos at jmax and cos_target recomputed exactly in fp32.

#define Bb 4
#define Ss 512
#define Dd 512
#define Vv 32000
#define ROWS (Bb * Ss)          // 2048
#define NTILE_M (ROWS / 128)    // 16
#define NTILE_N (Vv / 128)      // 250

typedef __attribute__((ext_vector_type(8))) short bf16x8;
typedef __attribute__((ext_vector_type(4))) float f32x4;

__device__ __forceinline__ float waveReduceSum(float x) {
#pragma unroll
  for (int m = 32; m >= 1; m >>= 1) x += __shfl_xor(x, m, 64);
  return x;
}

__device__ __forceinline__ unsigned short f2bf(float f) {
  unsigned u = __float_as_uint(f);
  unsigned r = (u + 0x7FFFu + ((u >> 16) & 1u)) >> 16;  // RNE; inputs finite
  return (unsigned short)r;
}

// monotonic key: for finite floats, key(a) < key(b) <=> a < b
__device__ __forceinline__ unsigned long long packSC(float s, int c) {
  unsigned b = __float_as_uint(s);
  unsigned key = b ^ ((b & 0x80000000u) ? 0xFFFFFFFFu : 0x80000000u);
  return ((unsigned long long)key << 32) | (unsigned)(~c);  // ~c: ties -> smaller col wins at max
}

__device__ __forceinline__ void async_ld16(const void* g, void* l) {
  __builtin_amdgcn_global_load_lds((const __attribute__((address_space(1))) void*)g,
                                   (__attribute__((address_space(3))) void*)l, 16, 0, 0);
}

// A: per-row prep. out_norm (fp32), u = out_norm - emb[target] (bf16 for GEMM),
// cos_target exact fp32.
__global__ __launch_bounds__(256) void prep_rows(
    const float* __restrict__ preds, const float* __restrict__ emb,
    const int* __restrict__ target,
    float* __restrict__ o_rows, short* __restrict__ u_bf,
    float* __restrict__ cos_tgt) {
  int row = blockIdx.x;
  int b = row >> 9, s = row & (Ss - 1);
  int tid = threadIdx.x;
  int wave = tid >> 6, lane = tid & 63;
  const float* p = preds + (size_t)b * Dd * Ss + s;
  float x0 = p[(size_t)tid * Ss];
  float x1 = p[(size_t)(tid + 256) * Ss];
  __shared__ float red[12];
  float ss = waveReduceSum(x0 * x0 + x1 * x1);
  if (lane == 0) red[wave] = ss;
  __syncthreads();
  float inv = 1.0f / fmaxf(sqrtf(red[0] + red[1] + red[2] + red[3]), 1e-12f);
  float o0 = x0 * inv, o1 = x1 * inv;
  o_rows[(size_t)row * Dd + tid] = o0;
  o_rows[(size_t)row * Dd + tid + 256] = o1;
  int t = target[row];
  const float* et = emb + (size_t)t * Dd;
  float e0 = et[tid], e1 = et[tid + 256];
  u_bf[(size_t)row * Dd + tid] = (short)f2bf(o0 - e0);
  u_bf[(size_t)row * Dd + tid + 256] = (short)f2bf(o1 - e1);
  float ss2 = waveReduceSum(e0 * e0 + e1 * e1);
  float dt = waveReduceSum(o0 * e0 + o1 * e1);
  if (lane == 0) { red[4 + wave] = ss2; red[8 + wave] = dt; }
  __syncthreads();
  if (tid == 0) {
    float n2 = red[4] + red[5] + red[6] + red[7];
    float dd = red[8] + red[9] + red[10] + red[11];
    cos_tgt[row] = dd * (1.0f / fmaxf(sqrtf(n2), 1e-12f));
  }
}

// B: voc_norm rows in bf16 + inv_norm fp32. One wave per v.
__global__ __launch_bounds__(256) void voc_prep(const float* __restrict__ emb,
                                                short* __restrict__ ebf,
                                                float* __restrict__ inv_norm) {
  int v = blockIdx.x * 4 + (threadIdx.x >> 6);
  int lane = threadIdx.x & 63;
  const float* e = emb + (size_t)v * Dd;
  float4 x0 = *(const float4*)(e + lane * 8);
  float4 x1 = *(const float4*)(e + lane * 8 + 4);
  float ss = x0.x * x0.x + x0.y * x0.y + x0.z * x0.z + x0.w * x0.w +
             x1.x * x1.x + x1.y * x1.y + x1.z * x1.z + x1.w * x1.w;
  ss = waveReduceSum(ss);
  float inv = 1.0f / fmaxf(sqrtf(ss), 1e-12f);
  bf16x8 o;
  o[0] = (short)f2bf(x0.x * inv); o[1] = (short)f2bf(x0.y * inv);
  o[2] = (short)f2bf(x0.z * inv); o[3] = (short)f2bf(x0.w * inv);
  o[4] = (short)f2bf(x1.x * inv); o[5] = (short)f2bf(x1.y * inv);
  o[6] = (short)f2bf(x1.z * inv); o[7] = (short)f2bf(x1.w * inv);
  *(bf16x8*)(ebf + (size_t)v * Dd + lane * 8) = o;
  if (lane == 0) inv_norm[v] = inv;
}

// C: 128x128-tile bf16 MFMA GEMM (gemm_bt) + per-row argmax epilogue.
// grid (16 m-tiles, 250 n-tiles), 256 threads = 2x2 waves of 64x64.
__global__ __launch_bounds__(256) void gemm_argmax(
    const short* __restrict__ u_bf, const short* __restrict__ ebf,
    unsigned long long* __restrict__ part) {
  __shared__ short sA[128 * 32];
  __shared__ short sB[128 * 32];
  int tm = blockIdx.x, tn = blockIdx.y;
  int tid = threadIdx.x;
  int w = tid >> 6, lane = tid & 63;
  int wm = w >> 1, wn = w & 1;

  // staging addresses: wave w stages rows [w*32, w*32+32) of each tile.
  const short* gA = u_bf + ((size_t)(tm * 128 + w * 32 + (lane >> 2)) * Dd) + (lane & 3) * 8;
  const short* gB = ebf + ((size_t)(tn * 128 + w * 32 + (lane >> 2)) * Dd) + (lane & 3) * 8;
  short* lA = &sA[(w * 32) * 32];
  short* lB = &sB[(w * 32) * 32];

  // fragment read base: row = (lane&15), k-chunk = (lane>>4)*8
  const short* pa = &sA[(lane & 15) * 32 + (lane >> 4) * 8];
  const short* pb = &sB[(lane & 15) * 32 + (lane >> 4) * 8];

  f32x4 acc[4][4];
  f32x4 z = {0.f, 0.f, 0.f, 0.f};
#pragma unroll
  for (int mi = 0; mi < 4; ++mi)
#pragma unroll
    for (int ni = 0; ni < 4; ++ni) acc[mi][ni] = z;

  for (int kk = 0; kk < Dd / 32; ++kk) {
    __syncthreads();  // previous compute done before overwrite
    async_ld16(gA + kk * 32, lA);
    async_ld16(gA + 16 * Dd + kk * 32, lA + 16 * 32);
    async_ld16(gB + kk * 32, lB);
    async_ld16(gB + 16 * Dd + kk * 32, lB + 16 * 32);
    __syncthreads();  // staging visible (vmcnt drained by barrier)
    bf16x8 af[4], bg[4];
#pragma unroll
    for (int mi = 0; mi < 4; ++mi)
      af[mi] = *(const bf16x8*)(pa + (wm * 64 + mi * 16) * 32);
#pragma unroll
    for (int ni = 0; ni < 4; ++ni)
      bg[ni] = *(const bf16x8*)(pb + (wn * 64 + ni * 16) * 32);
#pragma unroll
    for (int mi = 0; mi < 4; ++mi)
#pragma unroll
      for (int ni = 0; ni < 4; ++ni)
        acc[mi][ni] = __builtin_amdgcn_mfma_f32_16x16x32_bf16(af[mi], bg[ni], acc[mi][ni], 0, 0, 0);
  }

  // ---- argmax epilogue ----
  // C layout: col = lane&15, row = (lane>>4)*4 + reg
  float bs[4][4];  // [mi][reg]
  int bc[4][4];
  int col0 = tn * 128 + wn * 64 + (lane & 15);
#pragma unroll
  for (int mi = 0; mi < 4; ++mi) {
#pragma unroll
    for (int j = 0; j < 4; ++j) { bs[mi][j] = acc[mi][0][j]; bc[mi][j] = col0; }
#pragma unroll
    for (int ni = 1; ni < 4; ++ni) {
      int c = col0 + ni * 16;
#pragma unroll
      for (int j = 0; j < 4; ++j) {
        float v = acc[mi][ni][j];
        if (v > bs[mi][j]) { bs[mi][j] = v; bc[mi][j] = c; }  // strict >: earliest col kept
      }
    }
  }
  // butterfly across the 16 cols (masks 1,2,4,8 stay within the 16-lane group)
#pragma unroll
  for (int m = 1; m < 16; m <<= 1) {
#pragma unroll
    for (int mi = 0; mi < 4; ++mi)
#pragma unroll
      for (int j = 0; j < 4; ++j) {
        float os = __shfl_xor(bs[mi][j], m, 64);
        int oc = __shfl_xor(bc[mi][j], m, 64);
        if (os > bs[mi][j] || (os == bs[mi][j] && oc < bc[mi][j])) {
          bs[mi][j] = os;
          bc[mi][j] = oc;
        }
      }
  }
  // merge the two col-half waves via LDS, one packed write per row per block
  __syncthreads();  // done reading sA/sB; reuse as merge scratch
  float* sEs = (float*)sA;          // [2][128]
  int* sEc = (int*)sA + 256;        // [2][128]
  if ((lane & 15) == 0) {
    int q = lane >> 4;
#pragma unroll
    for (int mi = 0; mi < 4; ++mi)
#pragma unroll
      for (int j = 0; j < 4; ++j) {
        int rloc = wm * 64 + mi * 16 + q * 4 + j;
        sEs[wn * 128 + rloc] = bs[mi][j];
        sEc[wn * 128 + rloc] = bc[mi][j];
      }
  }
  __syncthreads();
  if (tid < 128) {
    float s0 = sEs[tid], s1 = sEs[128 + tid];
    int c0 = sEc[tid], c1 = sEc[128 + tid];
    if (s1 > s0 || (s1 == s0 && c1 < c0)) { s0 = s1; c0 = c1; }
    part[(size_t)tn * ROWS + tm * 128 + tid] = packSC(s0, c0);
  }
}

// D: per row — u64-max merge 250 partials, recompute cos at jmax in fp32, hinge.
__global__ __launch_bounds__(256) void row_final(
    const float* __restrict__ o_rows, const float* __restrict__ emb,
    const float* __restrict__ inv_norm, const float* __restrict__ cos_tgt,
    const int* __restrict__ target, const int* __restrict__ pad_id,
    const unsigned long long* __restrict__ part, float* __restrict__ diffs) {
  int wave = threadIdx.x >> 6, lane = threadIdx.x & 63;
  int row = blockIdx.x * 4 + wave;
  unsigned long long best = 0ull;  // any real packed value exceeds 0
  for (int t = lane; t < NTILE_N; t += 64) {
    unsigned long long p = part[(size_t)t * ROWS + row];
    if (p > best) best = p;
  }
#pragma unroll
  for (int m = 1; m < 64; m <<= 1) {
    unsigned long long o = __shfl_xor(best, m, 64);
    if (o > best) best = o;
  }
  int bi = (int)(~(unsigned)(best & 0xFFFFFFFFull));
  const float* o = o_rows + (size_t)row * Dd;
  const float* e = emb + (size_t)bi * Dd;
  float d = 0.f;
#pragma unroll
  for (int i = 0; i < Dd / 64; ++i) d += o[lane + 64 * i] * e[lane + 64 * i];
  d = waveReduceSum(d);
  if (lane == 0) {
    float cmax = d * inv_norm[bi];
    int t = target[row];
    float df = fmaxf(0.5f + cmax - cos_tgt[row], 0.0f);
    diffs[row] = (t != pad_id[0]) ? df : 0.0f;
  }
}

// F: masked mean.
__global__ __launch_bounds__(256) void reduce_final(
    const float* __restrict__ diffs, const int* __restrict__ target,
    const int* __restrict__ pad_id, float* __restrict__ out) {
  int tid = threadIdx.x;
  int pid = pad_id[0];
  float s = 0.f, c = 0.f;
  for (int i = tid; i < ROWS; i += 256) {
    s += diffs[i];
    c += (target[i] != pid) ? 1.0f : 0.0f;
  }
  s = waveReduceSum(s);
  c = waveReduceSum(c);
  __shared__ float rs[4], rc[4];
  int wave = tid >> 6, lane = tid & 63;
  if (lane == 0) { rs[wave] = s; rc[wave] = c; }
  __syncthreads();
  if (tid == 0) out[0] = (rs[0] + rs[1] + rs[2] + rs[3]) / (rc[0] + rc[1] + rc[2] + rc[3]);
}

extern "C" void kernel_launch(void* const* d_in, const int* in_sizes, int n_in,
                              void* d_out, int out_size, void* d_ws, size_t ws_size,
                              hipStream_t stream) {
  const float* preds = (const float*)d_in[0];
  const float* emb = (const float*)d_in[1];
  const int* target = (const int*)d_in[2];
  const int* pad_id = (const int*)d_in[3];
  char* ws = (char*)d_ws;
  // ws layout (bytes), total ~43.3 MB
  float* o_rows = (float*)ws;                               // 2048*512*4 = 4,194,304
  short* u_bf = (short*)(ws + 4194304);                     // 2048*512*2 = 2,097,152
  short* ebf = (short*)(ws + 6291456);                      // 32000*512*2 = 32,768,000
  float* inv_norm = (float*)(ws + 39059456);                // 32000*4 = 128,000
  float* cos_tgt = (float*)(ws + 39187456);                 // 2048*4
  unsigned long long* part = (unsigned long long*)(ws + 39195648);  // 250*2048*8 = 4,096,000
  float* diffs = (float*)(ws + 43291648);                   // 2048*4

  prep_rows<<<ROWS, 256, 0, stream>>>(preds, emb, target, o_rows, u_bf, cos_tgt);
  voc_prep<<<Vv / 4, 256, 0, stream>>>(emb, ebf, inv_norm);
  dim3 g(NTILE_M, NTILE_N);
  gemm_argmax<<<g, 256, 0, stream>>>(u_bf, ebf, part);
  row_final<<<ROWS / 4, 256, 0, stream>>>(o_rows, emb, inv_norm, cos_tgt, target,
                                          pad_id, part, diffs);
  reduce_final<<<1, 256, 0, stream>>>(diffs, target, pad_id, (float*)d_out);
}